// Round 3
// baseline (963.995 us; speedup 1.0000x reference)
//
#include <hip/hip_runtime.h>
#include <cstdint>
#include <cstddef>

#define F_IN 128
#define HID 16
#define NBUK 1024          // buckets = node >> 7
#define NPB  128           // nodes per bucket
#define CHUNK 8192         // edges per sort block

// ---------------- index-width detection ----------------
// int64 little-endian with values < 2^31 => every odd 32-bit word of the
// first 64 entries is zero. Flag: 1 = int64, 0 = int32.
__global__ void k_detect(const int* __restrict__ eidx, int* __restrict__ flag) {
    if (blockIdx.x == 0 && threadIdx.x == 0) {
        int all0 = 1;
        for (int i = 0; i < 64; ++i) {
            if (eidx[2 * i + 1] != 0) { all0 = 0; break; }
        }
        *flag = all0;
    }
}

__device__ __forceinline__ int ld_idx(const int* __restrict__ p, int e, int is64) {
    return is64 ? p[2 * e] : p[e];
}

// ---------------- bucket histogram (LDS-staged) ----------------
__launch_bounds__(256)
__global__ void k_bhist(const int* __restrict__ eidx, int E,
                        const int* __restrict__ flag, int* __restrict__ ghist) {
    __shared__ int lh[NBUK];
    int t = threadIdx.x;
    for (int i = t; i < NBUK; i += 256) lh[i] = 0;
    __syncthreads();
    int base = blockIdx.x * CHUNK;
    int cnt = min(CHUNK, E - base);
    int is64 = *flag;
    const int* colp = eidx + ((size_t)E << is64);
    for (int i = t; i < cnt; i += 256)
        atomicAdd(&lh[ld_idx(colp, base + i, is64) >> 7], 1);
    __syncthreads();
    for (int i = t; i < NBUK; i += 256)
        if (lh[i]) atomicAdd(&ghist[i], lh[i]);
}

// ---------------- scan of 1024 bucket counts (single block) ----------------
__global__ void k_bscan(const int* __restrict__ ghist, int E,
                        int* __restrict__ boff, int* __restrict__ gcur) {
    __shared__ int s[NBUK];
    int t = threadIdx.x;
    int v = ghist[t];
    s[t] = v;
    __syncthreads();
    for (int off = 1; off < NBUK; off <<= 1) {
        int a = (t >= off) ? s[t - off] : 0;
        __syncthreads();
        s[t] += a;
        __syncthreads();
    }
    int excl = s[t] - v;
    boff[t] = excl;
    gcur[t] = excl;
    if (t == NBUK - 1) boff[NBUK] = E;
}

// ------- bucket scatter with LDS staging (coalesced-run writes) -------
// pairs[k] = r | (c&127)<<20, grouped by bucket (c>>7)
__launch_bounds__(256)
__global__ void k_bscatter(const int* __restrict__ eidx, int E,
                           const int* __restrict__ flag,
                           int* __restrict__ gcur, uint32_t* __restrict__ pairs) {
    __shared__ int ls[NBUK + 1];
    __shared__ int lcur[NBUK];
    __shared__ int gb[NBUK];
    __shared__ int aux[256];
    __shared__ uint32_t staged[CHUNK];
    int t = threadIdx.x;
    int base = blockIdx.x * CHUNK;
    int cnt = min(CHUNK, E - base);
    int is64 = *flag;
    const int* rowp = eidx;
    const int* colp = eidx + ((size_t)E << is64);

    for (int i = t; i < NBUK; i += 256) ls[i] = 0;
    __syncthreads();
    // phase 1: local histogram
    for (int i = t; i < cnt; i += 256)
        atomicAdd(&ls[ld_idx(colp, base + i, is64) >> 7], 1);
    __syncthreads();
    // phase 2: block exclusive scan of 1024 counts (4 per thread)
    int c0 = ls[4 * t], c1 = ls[4 * t + 1], c2 = ls[4 * t + 2], c3 = ls[4 * t + 3];
    int sum4 = c0 + c1 + c2 + c3;
    aux[t] = sum4;
    __syncthreads();
    for (int off = 1; off < 256; off <<= 1) {
        int a = (t >= off) ? aux[t - off] : 0;
        __syncthreads();
        aux[t] += a;
        __syncthreads();
    }
    int excl = aux[t] - sum4;
    int e0 = excl, e1 = excl + c0, e2 = e1 + c1, e3 = e2 + c2;
    __syncthreads();
    ls[4 * t] = e0; ls[4 * t + 1] = e1; ls[4 * t + 2] = e2; ls[4 * t + 3] = e3;
    lcur[4 * t] = e0; lcur[4 * t + 1] = e1; lcur[4 * t + 2] = e2; lcur[4 * t + 3] = e3;
    if (c0) gb[4 * t]     = atomicAdd(&gcur[4 * t],     c0);
    if (c1) gb[4 * t + 1] = atomicAdd(&gcur[4 * t + 1], c1);
    if (c2) gb[4 * t + 2] = atomicAdd(&gcur[4 * t + 2], c2);
    if (c3) gb[4 * t + 3] = atomicAdd(&gcur[4 * t + 3], c3);
    if (t == 0) ls[NBUK] = cnt;
    __syncthreads();
    // phase 3: place packed edges into LDS, grouped by bucket
    for (int i = t; i < cnt; i += 256) {
        int c = ld_idx(colp, base + i, is64);
        int r = ld_idx(rowp, base + i, is64);
        int buk = c >> 7;
        int pos = atomicAdd(&lcur[buk], 1);
        staged[pos] = (uint32_t)r | ((uint32_t)(c & 127) << 20);
    }
    __syncthreads();
    // phase 4: linear write-out; bucket of slot i via binary search over ls
    for (int i = t; i < cnt; i += 256) {
        int lo = 0, hi = NBUK;
        while (hi - lo > 1) {
            int mid = (lo + hi) >> 1;
            if (ls[mid] <= i) lo = mid; else hi = mid;
        }
        pairs[gb[lo] + (i - ls[lo])] = staged[i];
    }
}

// ---------------- per-bucket degree -> dinv ----------------
__launch_bounds__(256)
__global__ void k_bdeg(const uint32_t* __restrict__ pairs, const int* __restrict__ boff,
                       float* __restrict__ dinv, int n) {
    __shared__ int cnt[NPB];
    int t = threadIdx.x;
    if (t < NPB) cnt[t] = 0;
    __syncthreads();
    int b = blockIdx.x;
    for (int k = boff[b] + t; k < boff[b + 1]; k += 256)
        atomicAdd(&cnt[pairs[k] >> 20], 1);
    __syncthreads();
    if (t < NPB) {
        int node = b * NPB + t;
        if (node < n) dinv[node] = rsqrtf((float)cnt[t] + 1.0f);
    }
}

// ---------------- h = x @ W1   [n,128] @ [128,16] ----------------
__launch_bounds__(256)
__global__ void k_gemm1(const float* __restrict__ x, const float* __restrict__ W1,
                        float* __restrict__ h, int n) {
    __shared__ float Wt[16 * 132];
    for (int i = threadIdx.x; i < F_IN * HID; i += 256) {
        int k = i >> 4, j = i & 15;
        Wt[j * 132 + k] = W1[i];
    }
    __syncthreads();
    int row = blockIdx.x * 16 + (threadIdx.x >> 4);
    int j = threadIdx.x & 15;
    if (row >= n) return;
    const float4* xr = (const float4*)(x + (size_t)row * F_IN);
    float acc = 0.f;
#pragma unroll
    for (int kk = 0; kk < 32; ++kk) {
        float4 xv = xr[kk];
        float4 wv = *(const float4*)&Wt[j * 132 + 4 * kk];
        acc += xv.x * wv.x + xv.y * wv.y + xv.z * wv.z + xv.w * wv.w;
    }
    h[(size_t)row * HID + j] = acc;
}

// ------- fused GCN layer: LDS-accumulated aggregation + epilogue matmul -------
// agg[cl][j] = sum over bucket edges (c==node) of h[r][j]*dinv[r]
// hrelu = relu(agg*dinv[c] + h[c]*dinv[c]^2 + bias)
// EPI 0: out0 = hrelu @ Wnext[16x16]          (next layer's pre-agg input)
// EPI 1: out0 = hrelu @ Wnext[0:16], out1 = hrelu @ Wnext[16:32]   (u, v)
template <int EPI>
__launch_bounds__(256)
__global__ void k_layer(const uint32_t* __restrict__ pairs, const int* __restrict__ boff,
                        const float* __restrict__ h, const float* __restrict__ dinv,
                        const float* __restrict__ bias, const float* __restrict__ Wnext,
                        float* __restrict__ out0, float* __restrict__ out1, int n) {
    __shared__ float acc[NPB * 17];
    __shared__ float Ws[512];
    __shared__ float bs[16];
    int t = threadIdx.x;
    int b = blockIdx.x;
    for (int i = t; i < NPB * 17; i += 256) acc[i] = 0.f;
    int nw = (EPI == 0) ? 256 : 512;
    for (int i = t; i < nw; i += 256) Ws[i] = Wnext[i];
    if (t < 16) bs[t] = bias[t];
    __syncthreads();
    int beg = boff[b], end = boff[b + 1];
    int g = t >> 4, j = t & 15;
    for (int k = beg + g; k < end; k += 16) {
        uint32_t p = pairs[k];                  // broadcast across 16 lanes
        int r = p & 0xFFFFF;
        int cl = p >> 20;
        atomicAdd(&acc[cl * 17 + j], h[(size_t)r * HID + j] * dinv[r]);
    }
    __syncthreads();
    int node0 = b * NPB;
#pragma unroll
    for (int it = 0; it < 8; ++it) {
        int cl = (t >> 4) + it * 16;
        int node = node0 + cl;
        if (node < n) {
            float di = dinv[node];
            float val = acc[cl * 17 + j] * di + h[(size_t)node * HID + j] * di * di + bs[j];
            acc[cl * 17 + j] = fmaxf(val, 0.f);
        }
    }
    __syncthreads();
#pragma unroll
    for (int it = 0; it < 8; ++it) {
        int cl = (t >> 4) + it * 16;
        int node = node0 + cl;
        if (node >= n) continue;
        float a0 = 0.f, a1 = 0.f;
#pragma unroll
        for (int k = 0; k < 16; ++k) {
            float hv = acc[cl * 17 + k];
            a0 += hv * Ws[k * 16 + j];
            if (EPI == 1) a1 += hv * Ws[(16 + k) * 16 + j];
        }
        out0[(size_t)node * HID + j] = a0;
        if (EPI == 1) out1[(size_t)node * HID + j] = a1;
    }
}

// ---------------- per-edge MLP + log_softmax ----------------
__launch_bounds__(256)
__global__ void k_edge(const int* __restrict__ eidx, int E, const int* __restrict__ flag,
                       const float* __restrict__ u, const float* __restrict__ v,
                       const float* __restrict__ fc1b, const float* __restrict__ fc2W,
                       const float* __restrict__ fc2b, float* __restrict__ out) {
    __shared__ float b1s[16], W2s[32], b2s[2];
    if (threadIdx.x < 16) b1s[threadIdx.x] = fc1b[threadIdx.x];
    if (threadIdx.x < 32) W2s[threadIdx.x] = fc2W[threadIdx.x];
    if (threadIdx.x < 2) b2s[threadIdx.x] = fc2b[threadIdx.x];
    __syncthreads();
    int e = blockIdx.x * blockDim.x + threadIdx.x;
    if (e >= E) return;
    int is64 = *flag;
    const int* rowp = eidx;
    const int* colp = eidx + ((size_t)E << is64);
    int r = ld_idx(rowp, e, is64);
    int c = ld_idx(colp, e, is64);
    const float4* up = (const float4*)(u + (size_t)r * HID);
    const float4* vp = (const float4*)(v + (size_t)c * HID);
    float l0 = b2s[0], l1 = b2s[1];
#pragma unroll
    for (int q = 0; q < 4; ++q) {
        float4 uu = up[q], vv = vp[q];
        float z;
        z = fmaxf(uu.x + vv.x + b1s[4 * q + 0], 0.f);
        l0 += z * W2s[(4 * q + 0) * 2 + 0]; l1 += z * W2s[(4 * q + 0) * 2 + 1];
        z = fmaxf(uu.y + vv.y + b1s[4 * q + 1], 0.f);
        l0 += z * W2s[(4 * q + 1) * 2 + 0]; l1 += z * W2s[(4 * q + 1) * 2 + 1];
        z = fmaxf(uu.z + vv.z + b1s[4 * q + 2], 0.f);
        l0 += z * W2s[(4 * q + 2) * 2 + 0]; l1 += z * W2s[(4 * q + 2) * 2 + 1];
        z = fmaxf(uu.w + vv.w + b1s[4 * q + 3], 0.f);
        l0 += z * W2s[(4 * q + 3) * 2 + 0]; l1 += z * W2s[(4 * q + 3) * 2 + 1];
    }
    float m = fmaxf(l0, l1);
    float e0 = __expf(l0 - m), e1 = __expf(l1 - m);
    float lse = m + __logf(e0 + e1);
    ((float2*)out)[e] = make_float2(l0 - lse, l1 - lse);
}

static inline size_t rnd4(size_t v) { return (v + 3) & ~(size_t)3; }

extern "C" void kernel_launch(void* const* d_in, const int* in_sizes, int n_in,
                              void* d_out, int out_size, void* d_ws, size_t ws_size,
                              hipStream_t stream) {
    const float* x    = (const float*)d_in[0];
    const int*   eidx = (const int*)d_in[1];
    const float* W1   = (const float*)d_in[2];
    const float* b1   = (const float*)d_in[3];
    const float* W2   = (const float*)d_in[4];
    const float* b2   = (const float*)d_in[5];
    const float* fc1W = (const float*)d_in[6];
    const float* fc1b = (const float*)d_in[7];
    const float* fc2W = (const float*)d_in[8];
    const float* fc2b = (const float*)d_in[9];

    const int n = in_sizes[0] / F_IN;   // 100000
    const int E = in_sizes[1] / 2;      // 3200000
    const int NBLK_SORT = (E + CHUNK - 1) / CHUNK;   // 391
    const int NBLK_BUK  = (n + NPB - 1) / NPB;       // 782

    // workspace carve-up
    float* ws = (float*)d_ws;
    size_t a = 0;
    float*    dinv  = ws + a;              a += rnd4(n);
    uint32_t* pairs = (uint32_t*)(ws + a); a += rnd4(E);
    int*      boff  = (int*)(ws + a);      a += rnd4(NBUK + 1);
    int*      gcur  = (int*)(ws + a);      a += NBUK;
    int*      ghist = (int*)(ws + a);      a += NBUK;
    int*      flag  = (int*)(ws + a);      a += 4;
    float*    bufA  = ws + a;              a += rnd4((size_t)n * HID);
    float*    bufB  = ws + a;              a += rnd4((size_t)n * HID);
    float*    bufC  = ws + a;              a += rnd4((size_t)n * HID);
    float* out = (float*)d_out;

    k_detect<<<1, 64, 0, stream>>>(eidx, flag);

    // ---- bucket sort of edges by destination bucket (shared by both layers) ----
    hipMemsetAsync(ghist, 0, NBUK * sizeof(int), stream);
    k_bhist<<<NBLK_SORT, 256, 0, stream>>>(eidx, E, flag, ghist);
    k_bscan<<<1, NBUK, 0, stream>>>(ghist, E, boff, gcur);
    k_bscatter<<<NBLK_SORT, 256, 0, stream>>>(eidx, E, flag, gcur, pairs);
    k_bdeg<<<NBLK_BUK, 256, 0, stream>>>(pairs, boff, dinv, n);

    // ---- dense prologue ----
    k_gemm1<<<(n + 15) / 16, 256, 0, stream>>>(x, W1, bufA, n);   // h1 = x@W1

    // ---- layer 1 (fused epilogue: h2in = relu(gcn)@W2) ----
    k_layer<0><<<NBLK_BUK, 256, 0, stream>>>(pairs, boff, bufA, dinv, b1, W2,
                                             bufB, nullptr, n);
    // ---- layer 2 (fused epilogue: u,v = relu(gcn)@fc1W halves) ----
    k_layer<1><<<NBLK_BUK, 256, 0, stream>>>(pairs, boff, bufB, dinv, b2, fc1W,
                                             bufA, bufC, n);
    // ---- edge MLP + log_softmax ----
    k_edge<<<(E + 255) / 256, 256, 0, stream>>>(eidx, E, flag, bufA, bufC,
                                                fc1b, fc2W, fc2b, out);
}

// Round 4
// 882.686 us; speedup vs baseline: 1.0921x; 1.0921x over previous
//
#include <hip/hip_runtime.h>
#include <hip/hip_fp16.h>
#include <cstdint>
#include <cstddef>

#define F_IN 128
#define HID 16
#define NBUK 1024          // bucket = node >> 7
#define NPB  128           // nodes per bucket
#define CHUNK 8192         // edges per sort block

// ---------------- index-width detection ----------------
// int64 little-endian with values < 2^31 => every odd 32-bit word of the
// first 64 entries is zero. Flag: 1 = int64, 0 = int32.
__global__ void k_detect(const int* __restrict__ eidx, int* __restrict__ flag) {
    if (blockIdx.x == 0 && threadIdx.x == 0) {
        int all0 = 1;
        for (int i = 0; i < 64; ++i) {
            if (eidx[2 * i + 1] != 0) { all0 = 0; break; }
        }
        *flag = all0;
    }
}

__device__ __forceinline__ int ld_idx(const int* __restrict__ p, int e, int is64) {
    return is64 ? p[2 * e] : p[e];
}

// ---------------- bucket histogram (LDS-staged) ----------------
__launch_bounds__(256)
__global__ void k_bhist(const int* __restrict__ eidx, int E,
                        const int* __restrict__ flag, int* __restrict__ ghist) {
    __shared__ int lh[NBUK];
    int t = threadIdx.x;
    for (int i = t; i < NBUK; i += 256) lh[i] = 0;
    __syncthreads();
    int base = blockIdx.x * CHUNK;
    int cnt = min(CHUNK, E - base);
    int is64 = *flag;
    const int* colp = eidx + ((size_t)E << is64);
    for (int i = t; i < cnt; i += 256)
        atomicAdd(&lh[ld_idx(colp, base + i, is64) >> 7], 1);
    __syncthreads();
    for (int i = t; i < NBUK; i += 256)
        if (lh[i]) atomicAdd(&ghist[i], lh[i]);
}

// ------- scan of 1024 bucket counts, padded to 64-entry alignment -------
__global__ void k_bscan(const int* __restrict__ ghist,
                        int* __restrict__ boff, int* __restrict__ gcur) {
    __shared__ int s[NBUK];
    int t = threadIdx.x;
    int v = (ghist[t] + 63) & ~63;     // padded count
    s[t] = v;
    __syncthreads();
    for (int off = 1; off < NBUK; off <<= 1) {
        int a = (t >= off) ? s[t - off] : 0;
        __syncthreads();
        s[t] += a;
        __syncthreads();
    }
    int excl = s[t] - v;
    boff[t] = excl;
    gcur[t] = excl;
    if (t == NBUK - 1) boff[NBUK] = s[t];
}

// ------- direct bucket scatter: LDS cursor per bucket, runs share L2 lines -------
// pairs[k] = r | (c&127)<<20, grouped by bucket (c>>7)
__launch_bounds__(256)
__global__ void k_bscatter(const int* __restrict__ eidx, int E,
                           const int* __restrict__ flag,
                           int* __restrict__ gcur, uint32_t* __restrict__ pairs) {
    __shared__ int lh[NBUK];
    __shared__ int lcur[NBUK];
    int t = threadIdx.x;
    for (int i = t; i < NBUK; i += 256) lh[i] = 0;
    __syncthreads();
    int base = blockIdx.x * CHUNK;
    int cnt = min(CHUNK, E - base);
    int is64 = *flag;
    const int* rowp = eidx;
    const int* colp = eidx + ((size_t)E << is64);
    for (int i = t; i < cnt; i += 256)
        atomicAdd(&lh[ld_idx(colp, base + i, is64) >> 7], 1);
    __syncthreads();
    for (int i = t; i < NBUK; i += 256) {
        int c = lh[i];
        lcur[i] = c ? atomicAdd(&gcur[i], c) : 0;   // reserve contiguous run
    }
    __syncthreads();
    for (int i = t; i < cnt; i += 256) {
        int c = ld_idx(colp, base + i, is64);
        int r = ld_idx(rowp, base + i, is64);
        int buk = c >> 7;
        int pos = atomicAdd(&lcur[buk], 1);
        pairs[pos] = (uint32_t)r | ((uint32_t)(c & 127) << 20);
    }
}

// ------- per-node degree -> dinv, and sentinel-fill the bucket padding -------
__launch_bounds__(256)
__global__ void k_bdeg(uint32_t* __restrict__ pairs, const int* __restrict__ boff,
                       const int* __restrict__ ghist, float* __restrict__ dinv, int n) {
    __shared__ int cnt[NPB];
    int t = threadIdx.x;
    if (t < NPB) cnt[t] = 0;
    __syncthreads();
    int b = blockIdx.x;
    int beg = boff[b];
    int realE = ghist[b];
    for (int k = beg + t; k < beg + realE; k += 256)
        atomicAdd(&cnt[pairs[k] >> 20], 1);
    __syncthreads();
    if (t < NPB) {
        int node = b * NPB + t;
        if (node < n) dinv[node] = rsqrtf((float)cnt[t] + 1.0f);
    }
    // fill padding with sentinel edges: r = n (zero row), cl = 0
    for (int k = beg + realE + t; k < boff[b + 1]; k += 256)
        pairs[k] = (uint32_t)n;
}

// ------- hs1 = (x @ W1) * dinv[row], fp16; row n = zeros (sentinel row) -------
__launch_bounds__(256)
__global__ void k_gemm1(const float* __restrict__ x, const float* __restrict__ W1,
                        const float* __restrict__ dinv, __half* __restrict__ hs, int n) {
    __shared__ float Wt[16 * 132];
    for (int i = threadIdx.x; i < F_IN * HID; i += 256) {
        int k = i >> 4, j = i & 15;
        Wt[j * 132 + k] = W1[i];
    }
    __syncthreads();
    int row = blockIdx.x * 16 + (threadIdx.x >> 4);
    int j = threadIdx.x & 15;
    if (row > n) return;
    if (row == n) { hs[(size_t)row * HID + j] = __float2half(0.f); return; }
    const float4* xr = (const float4*)(x + (size_t)row * F_IN);
    float acc = 0.f;
#pragma unroll
    for (int kk = 0; kk < 32; ++kk) {
        float4 xv = xr[kk];
        float4 wv = *(const float4*)&Wt[j * 132 + 4 * kk];
        acc += xv.x * wv.x + xv.y * wv.y + xv.z * wv.z + xv.w * wv.w;
    }
    hs[(size_t)row * HID + j] = __float2half(acc * dinv[row]);
}

// ------- fused GCN layer: lane-per-edge gather + LDS atomic accum + epilogue -------
// acc[cl] = hs[self] + sum_{edges->cl} hs[r]     (hs is pre-scaled by dinv[src])
// hrelu = relu(acc*dinv + bias)
// EPI 0: out0 = fp16( (hrelu @ Wnext) * dinv )        (next layer's hs)
// EPI 1: out0 = fp16(hrelu @ Wnext[0:16]) = u,  out1 = ...[16:32] = v
template <int EPI>
__launch_bounds__(256)
__global__ void k_layer(const uint32_t* __restrict__ pairs, const int* __restrict__ boff,
                        const __half* __restrict__ hs, const float* __restrict__ dinv,
                        const float* __restrict__ bias, const float* __restrict__ Wnext,
                        __half* __restrict__ out0, __half* __restrict__ out1, int n) {
    __shared__ float acc[NPB * 17];
    __shared__ float Ws[512];
    __shared__ float bs[16];
    int t = threadIdx.x;
    int b = blockIdx.x;
    int node0 = b * NPB;
    // init accumulator with the self-loop term
    for (int i = t; i < NPB * HID; i += 256) {
        int cl = i >> 4, j = i & 15;
        int node = node0 + cl;
        float sv = (node < n) ? __half2float(hs[(size_t)node * HID + j]) : 0.f;
        acc[cl * 17 + j] = sv;
    }
    int nw = (EPI == 0) ? 256 : 512;
    for (int i = t; i < nw; i += 256) Ws[i] = Wnext[i];
    if (t < 16) bs[t] = bias[t];
    __syncthreads();
    int beg = boff[b], end = boff[b + 1];
    for (int k = beg + t; k < end; k += 256) {
        uint32_t p = pairs[k];                 // coalesced 4B/lane
        int r = p & 0xFFFFF;
        int cl = p >> 20;
        const uint4* hp = (const uint4*)(hs + (size_t)r * HID);
        uint4 A = hp[0];                       // 2 independent 16B loads in flight
        uint4 B = hp[1];
        float* ar = &acc[cl * 17];
        float2 f;
        f = __half22float2(*(__half2*)&A.x); atomicAdd(&ar[0], f.x);  atomicAdd(&ar[1], f.y);
        f = __half22float2(*(__half2*)&A.y); atomicAdd(&ar[2], f.x);  atomicAdd(&ar[3], f.y);
        f = __half22float2(*(__half2*)&A.z); atomicAdd(&ar[4], f.x);  atomicAdd(&ar[5], f.y);
        f = __half22float2(*(__half2*)&A.w); atomicAdd(&ar[6], f.x);  atomicAdd(&ar[7], f.y);
        f = __half22float2(*(__half2*)&B.x); atomicAdd(&ar[8], f.x);  atomicAdd(&ar[9], f.y);
        f = __half22float2(*(__half2*)&B.y); atomicAdd(&ar[10], f.x); atomicAdd(&ar[11], f.y);
        f = __half22float2(*(__half2*)&B.z); atomicAdd(&ar[12], f.x); atomicAdd(&ar[13], f.y);
        f = __half22float2(*(__half2*)&B.w); atomicAdd(&ar[14], f.x); atomicAdd(&ar[15], f.y);
    }
    __syncthreads();
    // relu(acc*dinv + b) in place
#pragma unroll
    for (int it = 0; it < 8; ++it) {
        int cl = (t >> 4) + it * 16;
        int node = node0 + cl;
        int j = t & 15;
        if (node < n) {
            float di = dinv[node];
            acc[cl * 17 + j] = fmaxf(acc[cl * 17 + j] * di + bs[j], 0.f);
        }
    }
    __syncthreads();
    // epilogue matmul(s)
#pragma unroll
    for (int it = 0; it < 8; ++it) {
        int cl = (t >> 4) + it * 16;
        int node = node0 + cl;
        int j = t & 15;
        if (node < n) {
            float a0 = 0.f, a1 = 0.f;
#pragma unroll
            for (int k2 = 0; k2 < 16; ++k2) {
                float hv = acc[cl * 17 + k2];
                a0 += hv * Ws[k2 * 16 + j];
                if (EPI == 1) a1 += hv * Ws[(16 + k2) * 16 + j];
            }
            if (EPI == 0) {
                out0[(size_t)node * HID + j] = __float2half(a0 * dinv[node]);
            } else {
                out0[(size_t)node * HID + j] = __float2half(a0);
                out1[(size_t)node * HID + j] = __float2half(a1);
            }
        } else if (EPI == 0 && node == n) {
            out0[(size_t)node * HID + j] = __float2half(0.f);   // sentinel row
        }
    }
}

// ---------------- per-edge MLP + log_softmax (fp16 u,v gathers) ----------------
__launch_bounds__(256)
__global__ void k_edge(const int* __restrict__ eidx, int E, const int* __restrict__ flag,
                       const __half* __restrict__ u, const __half* __restrict__ v,
                       const float* __restrict__ fc1b, const float* __restrict__ fc2W,
                       const float* __restrict__ fc2b, float* __restrict__ out) {
    __shared__ float b1s[16], W2s[32], b2s[2];
    if (threadIdx.x < 16) b1s[threadIdx.x] = fc1b[threadIdx.x];
    if (threadIdx.x < 32) W2s[threadIdx.x] = fc2W[threadIdx.x];
    if (threadIdx.x < 2) b2s[threadIdx.x] = fc2b[threadIdx.x];
    __syncthreads();
    int e = blockIdx.x * blockDim.x + threadIdx.x;
    if (e >= E) return;
    int is64 = *flag;
    const int* rowp = eidx;
    const int* colp = eidx + ((size_t)E << is64);
    int r = ld_idx(rowp, e, is64);
    int c = ld_idx(colp, e, is64);
    const uint4* up = (const uint4*)(u + (size_t)r * HID);
    const uint4* vp = (const uint4*)(v + (size_t)c * HID);
    uint4 U0 = up[0], U1 = up[1], V0 = vp[0], V1 = vp[1];
    float l0 = b2s[0], l1 = b2s[1];
#define PROC(uw, vw, jb)                                                        \
    {                                                                           \
        float2 fu = __half22float2(*(__half2*)&(uw));                           \
        float2 fv = __half22float2(*(__half2*)&(vw));                           \
        float z = fmaxf(fu.x + fv.x + b1s[jb], 0.f);                            \
        l0 += z * W2s[2 * (jb)]; l1 += z * W2s[2 * (jb) + 1];                   \
        z = fmaxf(fu.y + fv.y + b1s[(jb) + 1], 0.f);                            \
        l0 += z * W2s[2 * (jb) + 2]; l1 += z * W2s[2 * (jb) + 3];               \
    }
    PROC(U0.x, V0.x, 0) PROC(U0.y, V0.y, 2) PROC(U0.z, V0.z, 4) PROC(U0.w, V0.w, 6)
    PROC(U1.x, V1.x, 8) PROC(U1.y, V1.y, 10) PROC(U1.z, V1.z, 12) PROC(U1.w, V1.w, 14)
#undef PROC
    float m = fmaxf(l0, l1);
    float e0 = __expf(l0 - m), e1 = __expf(l1 - m);
    float lse = m + __logf(e0 + e1);
    ((float2*)out)[e] = make_float2(l0 - lse, l1 - lse);
}

static inline size_t rnd4(size_t v) { return (v + 3) & ~(size_t)3; }

extern "C" void kernel_launch(void* const* d_in, const int* in_sizes, int n_in,
                              void* d_out, int out_size, void* d_ws, size_t ws_size,
                              hipStream_t stream) {
    const float* x    = (const float*)d_in[0];
    const int*   eidx = (const int*)d_in[1];
    const float* W1   = (const float*)d_in[2];
    const float* b1   = (const float*)d_in[3];
    const float* W2   = (const float*)d_in[4];
    const float* b2   = (const float*)d_in[5];
    const float* fc1W = (const float*)d_in[6];
    const float* fc1b = (const float*)d_in[7];
    const float* fc2W = (const float*)d_in[8];
    const float* fc2b = (const float*)d_in[9];

    const int n = in_sizes[0] / F_IN;   // 100000
    const int E = in_sizes[1] / 2;      // 3200000
    const int NBLK_SORT = (E + CHUNK - 1) / CHUNK;   // 391
    const int NBLK_BUK  = (n + NPB - 1) / NPB;       // 782
    const size_t EPAD = (size_t)E + NBUK * 64 + 64;

    // workspace carve-up (float units, 16B-aligned regions)
    float* ws = (float*)d_ws;
    size_t a = 0;
    float*    dinv  = ws + a;              a += rnd4(n);
    uint32_t* pairs = (uint32_t*)(ws + a); a += rnd4(EPAD);
    int*      boff  = (int*)(ws + a);      a += rnd4(NBUK + 1);
    int*      gcur  = (int*)(ws + a);      a += NBUK;
    int*      ghist = (int*)(ws + a);      a += NBUK;
    int*      flag  = (int*)(ws + a);      a += 4;
    __half*   hs1   = (__half*)(ws + a);   a += rnd4((size_t)(n + 1) * HID / 2);
    __half*   hs2   = (__half*)(ws + a);   a += rnd4((size_t)(n + 1) * HID / 2);
    __half*   ubuf  = (__half*)(ws + a);   a += rnd4((size_t)n * HID / 2);
    __half*   vbuf  = (__half*)(ws + a);   a += rnd4((size_t)n * HID / 2);
    float* out = (float*)d_out;

    k_detect<<<1, 64, 0, stream>>>(eidx, flag);

    // ---- bucket sort of edges by destination bucket (shared by both layers) ----
    hipMemsetAsync(ghist, 0, NBUK * sizeof(int), stream);
    k_bhist<<<NBLK_SORT, 256, 0, stream>>>(eidx, E, flag, ghist);
    k_bscan<<<1, NBUK, 0, stream>>>(ghist, boff, gcur);
    k_bscatter<<<NBLK_SORT, 256, 0, stream>>>(eidx, E, flag, gcur, pairs);
    k_bdeg<<<NBLK_BUK, 256, 0, stream>>>(pairs, boff, ghist, dinv, n);

    // ---- dense prologue: hs1 = (x@W1)*dinv (fp16, row n zeroed) ----
    k_gemm1<<<(n + 16) / 16, 256, 0, stream>>>(x, W1, dinv, hs1, n);

    // ---- layer 1 (epilogue: hs2 = relu(gcn)@W2 * dinv, fp16) ----
    k_layer<0><<<NBLK_BUK, 256, 0, stream>>>(pairs, boff, hs1, dinv, b1, W2,
                                             hs2, nullptr, n);
    // ---- layer 2 (epilogue: u,v = relu(gcn)@fc1W halves, fp16) ----
    k_layer<1><<<NBLK_BUK, 256, 0, stream>>>(pairs, boff, hs2, dinv, b2, fc1W,
                                             ubuf, vbuf, n);
    // ---- edge MLP + log_softmax ----
    k_edge<<<(E + 255) / 256, 256, 0, stream>>>(eidx, E, flag, ubuf, vbuf,
                                                fc1b, fc2W, fc2b, out);
}

// Round 5
// 271.456 us; speedup vs baseline: 3.5512x; 3.2517x over previous
//
#include <hip/hip_runtime.h>
#include <hip/hip_fp16.h>
#include <cstdint>
#include <cstddef>

#define F_IN 128
#define HID 16
#define NBUK 1024          // bucket = node >> 7
#define NPB  128           // nodes per bucket
#define CHUNK 8192         // edges per sort block

// ---------------- index-width detection ----------------
// int64 little-endian with values < 2^31 => every odd 32-bit word of the
// first 64 entries is zero. Flag: 1 = int64, 0 = int32.
__global__ void k_detect(const int* __restrict__ eidx, int* __restrict__ flag) {
    if (blockIdx.x == 0 && threadIdx.x == 0) {
        int all0 = 1;
        for (int i = 0; i < 64; ++i) {
            if (eidx[2 * i + 1] != 0) { all0 = 0; break; }
        }
        *flag = all0;
    }
}

__device__ __forceinline__ int ld_idx(const int* __restrict__ p, int e, int is64) {
    return is64 ? p[2 * e] : p[e];
}

// ---------------- bucket histogram (LDS-staged, int atomics) ----------------
__launch_bounds__(256)
__global__ void k_bhist(const int* __restrict__ eidx, int E,
                        const int* __restrict__ flag, int* __restrict__ ghist) {
    __shared__ int lh[NBUK];
    int t = threadIdx.x;
    for (int i = t; i < NBUK; i += 256) lh[i] = 0;
    __syncthreads();
    int base = blockIdx.x * CHUNK;
    int cnt = min(CHUNK, E - base);
    int is64 = *flag;
    const int* colp = eidx + ((size_t)E << is64);
    for (int i = t; i < cnt; i += 256)
        atomicAdd(&lh[ld_idx(colp, base + i, is64) >> 7], 1);
    __syncthreads();
    for (int i = t; i < NBUK; i += 256)
        if (lh[i]) atomicAdd(&ghist[i], lh[i]);
}

// ---------------- exact scan of 1024 bucket counts ----------------
__global__ void k_bscan(const int* __restrict__ ghist, int E,
                        int* __restrict__ boff, int* __restrict__ gcur) {
    __shared__ int s[NBUK];
    int t = threadIdx.x;
    int v = ghist[t];
    s[t] = v;
    __syncthreads();
    for (int off = 1; off < NBUK; off <<= 1) {
        int a = (t >= off) ? s[t - off] : 0;
        __syncthreads();
        s[t] += a;
        __syncthreads();
    }
    int excl = s[t] - v;
    boff[t] = excl;
    gcur[t] = excl;
    if (t == NBUK - 1) boff[NBUK] = E;
}

// ------- bucket scatter: LDS cursor per bucket, runs share L2 lines -------
// pairs[k] = r | (c&127)<<20, grouped by bucket (c>>7)
__launch_bounds__(256)
__global__ void k_bscatter(const int* __restrict__ eidx, int E,
                           const int* __restrict__ flag,
                           int* __restrict__ gcur, uint32_t* __restrict__ pairs) {
    __shared__ int lh[NBUK];
    __shared__ int lcur[NBUK];
    int t = threadIdx.x;
    for (int i = t; i < NBUK; i += 256) lh[i] = 0;
    __syncthreads();
    int base = blockIdx.x * CHUNK;
    int cnt = min(CHUNK, E - base);
    int is64 = *flag;
    const int* rowp = eidx;
    const int* colp = eidx + ((size_t)E << is64);
    for (int i = t; i < cnt; i += 256)
        atomicAdd(&lh[ld_idx(colp, base + i, is64) >> 7], 1);
    __syncthreads();
    for (int i = t; i < NBUK; i += 256) {
        int c = lh[i];
        lcur[i] = c ? atomicAdd(&gcur[i], c) : 0;   // reserve contiguous run
    }
    __syncthreads();
    for (int i = t; i < cnt; i += 256) {
        int c = ld_idx(colp, base + i, is64);
        int r = ld_idx(rowp, base + i, is64);
        int buk = c >> 7;
        int pos = atomicAdd(&lcur[buk], 1);
        pairs[pos] = (uint32_t)r | ((uint32_t)(c & 127) << 20);
    }
}

// ------- per-bucket counting sort -> full CSR (srcs, noff) + dinv -------
__launch_bounds__(256)
__global__ void k_bsort(const uint32_t* __restrict__ pairs, const int* __restrict__ boff,
                        int* __restrict__ srcs, int* __restrict__ noff,
                        float* __restrict__ dinv, int n) {
    __shared__ int cnt[NPB];
    __shared__ int scn[NPB];
    int t = threadIdx.x;
    int b = blockIdx.x;
    if (t < NPB) cnt[t] = 0;
    __syncthreads();
    int beg = boff[b], end = boff[b + 1];
    for (int k = beg + t; k < end; k += 256)
        atomicAdd(&cnt[pairs[k] >> 20], 1);
    __syncthreads();
    if (t < NPB) scn[t] = cnt[t];
    __syncthreads();
    for (int off = 1; off < NPB; off <<= 1) {
        int v = 0;
        if (t < NPB && t >= off) v = scn[t - off];
        __syncthreads();
        if (t < NPB) scn[t] += v;
        __syncthreads();
    }
    if (t < NPB) {
        int node = b * NPB + t;
        int excl = scn[t] - cnt[t];
        if (node <= n) noff[node] = beg + excl;      // node==n -> E (last bucket)
        if (node < n)  dinv[node] = rsqrtf((float)cnt[t] + 1.0f);
        cnt[t] = beg + excl;                         // reuse as cursor
    }
    __syncthreads();
    for (int k = beg + t; k < end; k += 256) {
        uint32_t p = pairs[k];
        int pos = atomicAdd(&cnt[p >> 20], 1);
        srcs[pos] = (int)(p & 0xFFFFF);
    }
}

// ------- hs1 = (x @ W1) * dinv[row], fp16 ----------------
__launch_bounds__(256)
__global__ void k_gemm1(const float* __restrict__ x, const float* __restrict__ W1,
                        const float* __restrict__ dinv, __half* __restrict__ hs, int n) {
    __shared__ float Wt[16 * 132];
    for (int i = threadIdx.x; i < F_IN * HID; i += 256) {
        int k = i >> 4, j = i & 15;
        Wt[j * 132 + k] = W1[i];
    }
    __syncthreads();
    int row = blockIdx.x * 16 + (threadIdx.x >> 4);
    int j = threadIdx.x & 15;
    if (row >= n) return;
    const float4* xr = (const float4*)(x + (size_t)row * F_IN);
    float acc = 0.f;
#pragma unroll
    for (int kk = 0; kk < 32; ++kk) {
        float4 xv = xr[kk];
        float4 wv = *(const float4*)&Wt[j * 132 + 4 * kk];
        acc += xv.x * wv.x + xv.y * wv.y + xv.z * wv.z + xv.w * wv.w;
    }
    hs[(size_t)row * HID + j] = __float2half(acc * dinv[row]);
}

// ------- fused GCN layer: CSR gather, register accumulate, LDS-bounce epilogue -------
// Each 16-lane group owns one node i; lane j owns feature j.
// acc = hs[i][j] + sum_{r in N(i)} hs[r][j]        (hs pre-scaled by dinv[src])
// hrelu[j] = relu(acc * dinv[i] + bias[j])
// EPI 0: out0 = fp16( (hrelu @ Wnext) * dinv )     (next layer's hs)
// EPI 1: out0 = fp16(hrelu @ Wnext[0:16]) = u, out1 = ...[16:32] = v
// NOTE: n % 16 == 0 (100000), so no partial groups and barriers are uniform.
template <int EPI>
__launch_bounds__(256)
__global__ void k_layer(const int* __restrict__ srcs, const int* __restrict__ noff,
                        const __half* __restrict__ hs, const float* __restrict__ dinv,
                        const float* __restrict__ bias, const float* __restrict__ Wnext,
                        __half* __restrict__ out0, __half* __restrict__ out1) {
    __shared__ float Ws[512];
    __shared__ float bs[16];
    __shared__ float srow[16 * 17];
    int t = threadIdx.x;
    int nw = (EPI == 0) ? 256 : 512;
    for (int i = t; i < nw; i += 256) Ws[i] = Wnext[i];
    if (t < 16) bs[t] = bias[t];
    __syncthreads();

    int i = blockIdx.x * 16 + (t >> 4);    // node
    int j = t & 15;                        // feature
    int beg = noff[i], end = noff[i + 1];
    float acc = __half2float(hs[(size_t)i * HID + j]);   // self-loop term

    int kb = beg;
    for (; kb + 16 <= end; kb += 16) {
        int idx = srcs[kb + j];            // 16-lane coalesced prefetch
#pragma unroll
        for (int m = 0; m < 16; ++m) {
            int r = __shfl(idx, m, 16);    // broadcast within the 16-lane group
            acc += __half2float(hs[(size_t)r * HID + j]);
        }
    }
    if (kb < end) {
        int lim = end - kb;
        int idx = srcs[kb + ((j < lim) ? j : (lim - 1))];
        for (int m = 0; m < lim; ++m) {
            int r = __shfl(idx, m, 16);
            acc += __half2float(hs[(size_t)r * HID + j]);
        }
    }

    float di = dinv[i];
    float hrelu = fmaxf(acc * di + bs[j], 0.f);
    int ln = t >> 4;
    __syncthreads();                        // protect srow reuse across grid-strided... (uniform)
    srow[ln * 17 + j] = hrelu;
    __syncthreads();
    float a0 = 0.f, a1 = 0.f;
#pragma unroll
    for (int k = 0; k < 16; ++k) {
        float hv = srow[ln * 17 + k];
        a0 += hv * Ws[k * 16 + j];
        if (EPI == 1) a1 += hv * Ws[(16 + k) * 16 + j];
    }
    if (EPI == 0) {
        out0[(size_t)i * HID + j] = __float2half(a0 * di);
    } else {
        out0[(size_t)i * HID + j] = __float2half(a0);
        out1[(size_t)i * HID + j] = __float2half(a1);
    }
}

// ---------------- per-edge MLP + log_softmax (fp16 u,v gathers) ----------------
__launch_bounds__(256)
__global__ void k_edge(const int* __restrict__ eidx, int E, const int* __restrict__ flag,
                       const __half* __restrict__ u, const __half* __restrict__ v,
                       const float* __restrict__ fc1b, const float* __restrict__ fc2W,
                       const float* __restrict__ fc2b, float* __restrict__ out) {
    __shared__ float b1s[16], W2s[32], b2s[2];
    if (threadIdx.x < 16) b1s[threadIdx.x] = fc1b[threadIdx.x];
    if (threadIdx.x < 32) W2s[threadIdx.x] = fc2W[threadIdx.x];
    if (threadIdx.x < 2) b2s[threadIdx.x] = fc2b[threadIdx.x];
    __syncthreads();
    int e = blockIdx.x * blockDim.x + threadIdx.x;
    if (e >= E) return;
    int is64 = *flag;
    const int* rowp = eidx;
    const int* colp = eidx + ((size_t)E << is64);
    int r = ld_idx(rowp, e, is64);
    int c = ld_idx(colp, e, is64);
    const uint4* up = (const uint4*)(u + (size_t)r * HID);
    const uint4* vp = (const uint4*)(v + (size_t)c * HID);
    uint4 U0 = up[0], U1 = up[1], V0 = vp[0], V1 = vp[1];
    float l0 = b2s[0], l1 = b2s[1];
#define PROC(uw, vw, jb)                                                        \
    {                                                                           \
        float2 fu = __half22float2(*(__half2*)&(uw));                           \
        float2 fv = __half22float2(*(__half2*)&(vw));                           \
        float z = fmaxf(fu.x + fv.x + b1s[jb], 0.f);                            \
        l0 += z * W2s[2 * (jb)]; l1 += z * W2s[2 * (jb) + 1];                   \
        z = fmaxf(fu.y + fv.y + b1s[(jb) + 1], 0.f);                            \
        l0 += z * W2s[2 * (jb) + 2]; l1 += z * W2s[2 * (jb) + 3];               \
    }
    PROC(U0.x, V0.x, 0) PROC(U0.y, V0.y, 2) PROC(U0.z, V0.z, 4) PROC(U0.w, V0.w, 6)
    PROC(U1.x, V1.x, 8) PROC(U1.y, V1.y, 10) PROC(U1.z, V1.z, 12) PROC(U1.w, V1.w, 14)
#undef PROC
    float m = fmaxf(l0, l1);
    float e0 = __expf(l0 - m), e1 = __expf(l1 - m);
    float lse = m + __logf(e0 + e1);
    ((float2*)out)[e] = make_float2(l0 - lse, l1 - lse);
}

static inline size_t rnd4(size_t v) { return (v + 3) & ~(size_t)3; }

extern "C" void kernel_launch(void* const* d_in, const int* in_sizes, int n_in,
                              void* d_out, int out_size, void* d_ws, size_t ws_size,
                              hipStream_t stream) {
    const float* x    = (const float*)d_in[0];
    const int*   eidx = (const int*)d_in[1];
    const float* W1   = (const float*)d_in[2];
    const float* b1   = (const float*)d_in[3];
    const float* W2   = (const float*)d_in[4];
    const float* b2   = (const float*)d_in[5];
    const float* fc1W = (const float*)d_in[6];
    const float* fc1b = (const float*)d_in[7];
    const float* fc2W = (const float*)d_in[8];
    const float* fc2b = (const float*)d_in[9];

    const int n = in_sizes[0] / F_IN;   // 100000  (divisible by 16)
    const int E = in_sizes[1] / 2;      // 3200000
    const int NBLK_SORT = (E + CHUNK - 1) / CHUNK;   // 391
    const int NBLK_BUK  = (n + NPB - 1) / NPB;       // 782

    // workspace carve-up (float units, 16B-aligned regions)
    float* ws = (float*)d_ws;
    size_t a = 0;
    float*    dinv  = ws + a;              a += rnd4(n);
    uint32_t* pairs = (uint32_t*)(ws + a); a += rnd4(E);
    int*      srcs  = (int*)(ws + a);      a += rnd4(E);
    int*      noff  = (int*)(ws + a);      a += rnd4(n + 1);
    int*      boff  = (int*)(ws + a);      a += rnd4(NBUK + 1);
    int*      gcur  = (int*)(ws + a);      a += NBUK;
    int*      ghist = (int*)(ws + a);      a += NBUK;
    int*      flag  = (int*)(ws + a);      a += 4;
    __half*   hs1   = (__half*)(ws + a);   a += rnd4((size_t)n * HID / 2);
    __half*   hs2   = (__half*)(ws + a);   a += rnd4((size_t)n * HID / 2);
    __half*   ubuf  = (__half*)(ws + a);   a += rnd4((size_t)n * HID / 2);
    __half*   vbuf  = (__half*)(ws + a);   a += rnd4((size_t)n * HID / 2);
    float* out = (float*)d_out;

    k_detect<<<1, 64, 0, stream>>>(eidx, flag);

    // ---- two-level bucket sort -> per-node CSR (shared by both layers) ----
    hipMemsetAsync(ghist, 0, NBUK * sizeof(int), stream);
    k_bhist<<<NBLK_SORT, 256, 0, stream>>>(eidx, E, flag, ghist);
    k_bscan<<<1, NBUK, 0, stream>>>(ghist, E, boff, gcur);
    k_bscatter<<<NBLK_SORT, 256, 0, stream>>>(eidx, E, flag, gcur, pairs);
    k_bsort<<<NBLK_BUK, 256, 0, stream>>>(pairs, boff, srcs, noff, dinv, n);

    // ---- dense prologue: hs1 = (x@W1)*dinv (fp16) ----
    k_gemm1<<<(n + 15) / 16, 256, 0, stream>>>(x, W1, dinv, hs1, n);

    // ---- layer 1 (epilogue: hs2 = relu(gcn)@W2 * dinv, fp16) ----
    k_layer<0><<<n / 16, 256, 0, stream>>>(srcs, noff, hs1, dinv, b1, W2, hs2, nullptr);
    // ---- layer 2 (epilogue: u,v = relu(gcn)@fc1W halves, fp16) ----
    k_layer<1><<<n / 16, 256, 0, stream>>>(srcs, noff, hs2, dinv, b2, fc1W, ubuf, vbuf);
    // ---- edge MLP + log_softmax ----
    k_edge<<<(E + 255) / 256, 256, 0, stream>>>(eidx, E, flag, ubuf, vbuf,
                                                fc1b, fc2W, fc2b, out);
}